// Round 4
// baseline (291.203 us; speedup 1.0000x reference)
//
#include <hip/hip_runtime.h>
#include <math.h>

#define TPB 256

typedef _Float16 half8 __attribute__((ext_vector_type(8)));
typedef float f32x4 __attribute__((ext_vector_type(4)));

// ---- XOR swizzle for the [64][64] f16 act tile (row = 128B = 32 banks).
// 16B chunk index c = col>>3 gets c ^= (row&7): A-fragment reads (16 lanes,
// same chunk col, 16 different rows) go from 16-way bank conflict to 2-way.
// Returned in _Float16 units; 8-half (16B) aligned when col%8==0.
__device__ __forceinline__ int swz(int row, int col) {
    return row * 64 + ((((col >> 3) ^ row) & 7) << 3) + (col & 7);
}

// Branchless GELU via Abramowitz-Stegun 7.1.26 erf (|abs err| <= 1.5e-7).
__device__ __forceinline__ float gelu_fast(float t) {
    float z = t * 0.70710678118654752440f;     // t / sqrt(2)
    float a = fabsf(z);
    float tau = __builtin_amdgcn_rcpf(fmaf(0.3275911f, a, 1.0f)); // 1/(1+p*a)
    float poly = fmaf(1.061405429f, tau, -1.453152027f);
    poly = fmaf(poly, tau, 1.421413741f);
    poly = fmaf(poly, tau, -0.284496736f);
    poly = fmaf(poly, tau, 0.254829592f);
    poly = poly * tau;
    float e = __expf(-a * a);                  // v_exp_f32
    float erf_a = fmaf(-poly, e, 1.0f);        // erf(|z|)
    float erf_z = copysignf(erf_a, z);
    return 0.5f * t * (1.0f + erf_z);
}

// ---- setup kernel: build fragment-ordered f16 hi/lo weights in workspace.
// Layout: half8 frag[L][nt][s][hl][lane]  (3*4*2*2*64 half8 = 48KB).
// Main-kernel B-load is then one perfectly-coalesced global_load_dwordx4 per
// (nt,s,hl): lane l reads frag[...][l]. Same 48KB for every block -> L1/L2
// resident broadcast; frees 48KB of LDS -> 4 blocks/CU instead of 1.
__global__ void weight_stage_kernel(const float* __restrict__ W1,
                                    const float* __restrict__ W2,
                                    const float* __restrict__ W3,
                                    _Float16* __restrict__ wsW) {
    const int idx = blockIdx.x * 256 + threadIdx.x;  // 12288 (L,nt,s,lane,e)
    if (idx >= 3 * 4 * 2 * 64 * 8) return;
    const int e    = idx & 7;
    const int lane = (idx >> 3) & 63;
    const int s    = (idx >> 9) & 1;
    const int nt   = (idx >> 10) & 3;
    const int L    = idx >> 12;
    const int g = lane >> 4, i = lane & 15;
    const int k = 32 * s + 8 * g + e;     // K index this slot consumes
    const int n = 16 * nt + i;            // N index this lane owns
    const float* W = (L == 0) ? W1 : (L == 1) ? W2 : W3;
    const int K = (L == 0) ? 33 : 64;
    const float val = (k < K) ? W[k * 64 + n] : 0.0f;  // W is [k][n]
    const _Float16 hi = (_Float16)val;
    const size_t base = ((((size_t)L * 4 + nt) * 2 + s) * 2) * 512
                        + (size_t)lane * 8 + e;
    wsW[base]       = hi;                              // hl=0
    wsW[base + 512] = (_Float16)(val - (float)hi);     // hl=1
}

// One MLP layer on a wave's 64x64 tile via mfma_f32_16x16x32_f16.
// A/B K-slot mapping cancels (HW pairs A-slot(g,e) with B-slot(g,e)); only
// the C/D map (col=lane&15, row=(lane>>4)*4+reg -- HW-verified) is relied on.
// Weights f16 hi+lo split (exact to ~2^-22). B-fragments come straight from
// the fragment-ordered global buffer (L1-hot). LN on f32 D fragments via
// shfl_xor over the 16-lane group.
template<bool LAST>
__device__ __forceinline__ void mfma_layer(
    _Float16* actB,                       // this wave's swizzled 64x64 tile
    const _Float16* __restrict__ wsL,     // frag[nt][s][hl][lane] for layer
    const float* bias, const float* gg, const float* bb,
    float* outp, int rowbase, int nrows)
{
    const int l = threadIdx.x & 63;
    const int g = l >> 4, i = l & 15;

    // B fragments: coalesced half8 loads, reused across all 4 M-tiles.
    const half8* Bp = reinterpret_cast<const half8*>(wsL);
    half8 Bh[4][2], Bl[4][2];
#pragma unroll
    for (int nt = 0; nt < 4; ++nt) {
#pragma unroll
        for (int s = 0; s < 2; ++s) {
            Bh[nt][s] = Bp[((nt * 2 + s) * 2 + 0) * 64 + l];
            Bl[nt][s] = Bp[((nt * 2 + s) * 2 + 1) * 64 + l];
        }
    }
    float bv[4], gv[4], bev[4];
#pragma unroll
    for (int nt = 0; nt < 4; ++nt) {
        bv[nt] = bias[16 * nt + i];
        if (!LAST) { gv[nt] = gg[16 * nt + i]; bev[nt] = bb[16 * nt + i]; }
    }
    const bool full = LAST && (rowbase + 63 < nrows);

#pragma unroll
    for (int t = 0; t < 4; ++t) {
        // A fragments for M-tile t (rows 16t..16t+15), K-steps 0,1 (swizzled)
        const half8 A0 = *(const half8*)&actB[swz(16 * t + i, 8 * g)];
        const half8 A1 = *(const half8*)&actB[swz(16 * t + i, 32 + 8 * g)];
        f32x4 D[4];
#pragma unroll
        for (int nt = 0; nt < 4; ++nt) {
            f32x4 d = {bv[nt], bv[nt], bv[nt], bv[nt]};
            d = __builtin_amdgcn_mfma_f32_16x16x32_f16(A0, Bh[nt][0], d, 0, 0, 0);
            d = __builtin_amdgcn_mfma_f32_16x16x32_f16(A1, Bh[nt][1], d, 0, 0, 0);
            d = __builtin_amdgcn_mfma_f32_16x16x32_f16(A0, Bl[nt][0], d, 0, 0, 0);
            d = __builtin_amdgcn_mfma_f32_16x16x32_f16(A1, Bl[nt][1], d, 0, 0, 0);
            D[nt] = d;
        }
        if (LAST) {
            // Store D fragments to global: row=16t+4g+reg, col=16nt+i
#pragma unroll
            for (int nt = 0; nt < 4; ++nt) {
#pragma unroll
                for (int r = 0; r < 4; ++r) {
                    const int grow = rowbase + 16 * t + 4 * g + r;
                    if (full || grow < nrows)
                        outp[(size_t)grow * 64 + 16 * nt + i] = D[nt][r];
                }
            }
        } else {
            // LN over the row's 64 values: per-lane N-tile partials (per
            // reg=row) + shfl_xor reduce across the 16 lanes of this group.
            f32x4 s4 = (D[0] + D[1]) + (D[2] + D[3]);
#pragma unroll
            for (int m = 1; m < 16; m <<= 1) {
                f32x4 o;
                o[0] = __shfl_xor(s4[0], m);
                o[1] = __shfl_xor(s4[1], m);
                o[2] = __shfl_xor(s4[2], m);
                o[3] = __shfl_xor(s4[3], m);
                s4 += o;
            }
            const f32x4 mean = s4 * 0.015625f;
            f32x4 vv = {0.f, 0.f, 0.f, 0.f};
#pragma unroll
            for (int nt = 0; nt < 4; ++nt) {
                f32x4 dd = D[nt] - mean;
                vv += dd * dd;
            }
#pragma unroll
            for (int m = 1; m < 16; m <<= 1) {
                f32x4 o;
                o[0] = __shfl_xor(vv[0], m);
                o[1] = __shfl_xor(vv[1], m);
                o[2] = __shfl_xor(vv[2], m);
                o[3] = __shfl_xor(vv[3], m);
                vv += o;
            }
            f32x4 rstd;
#pragma unroll
            for (int r = 0; r < 4; ++r)
                rstd[r] = rsqrtf(vv[r] * 0.015625f + 1e-5f);
            // normalize + GELU + write back transposed (swizzled, f16).
            // Tile t's output rows [16t,16t+16) are exactly the rows this
            // iteration already consumed -> no intra-layer hazard.
#pragma unroll
            for (int nt = 0; nt < 4; ++nt) {
#pragma unroll
                for (int r = 0; r < 4; ++r) {
                    float xx = (D[nt][r] - mean[r]) * rstd[r] * gv[nt] + bev[nt];
                    actB[swz(16 * t + 4 * g + r, 16 * nt + i)] =
                        (_Float16)gelu_fast(xx);
                }
            }
        }
    }
    if (!LAST) asm volatile("s_waitcnt lgkmcnt(0)" ::: "memory");
}

// LDS ~35KB -> 4 blocks/CU (16 waves/CU, 4 waves/SIMD).
// __launch_bounds__(256,4): 4 blocks * 4 waves = 16 waves/CU -> VGPR cap 128
// (empirical: cap = 2048/wavesPerCU; this code family compiles ~120-128).
__global__ __launch_bounds__(TPB, 4) void walsh_mlp_kernel(
    const int* __restrict__ tt,
    const float* __restrict__ b1,
    const float* __restrict__ g1, const float* __restrict__ be1,
    const float* __restrict__ b2,
    const float* __restrict__ g2, const float* __restrict__ be2,
    const float* __restrict__ b3,
    const _Float16* __restrict__ wsW,
    float* __restrict__ out, int nrows)
{
    __shared__ __align__(16) _Float16 sAct[4][64][64]; // per-wave act tiles
    __shared__ float sP[7 * 64];   // g1,be1,g2,be2,b1,b2,b3
    __shared__ float entLUT[33];   // -p*log(p+1e-10), p=(2i)^2/4096

    const int tid = threadIdx.x;
    if (tid < 64) {
        sP[tid]       = g1[tid];
        sP[64 + tid]  = be1[tid];
        sP[128 + tid] = g2[tid];
        sP[192 + tid] = be2[tid];
        sP[256 + tid] = b1[tid];
        sP[320 + tid] = b2[tid];
        sP[384 + tid] = b3[tid];
    }
    if (tid < 33) {
        const float a = 2.0f * (float)tid;
        const float p = (a * a) * 2.44140625e-4f;   // /4096 exact
        entLUT[tid] = -(p * __logf(p + 1e-10f));
    }
    __syncthreads();

    const int row = blockIdx.x * TPB + tid;
    const int rowc = (row < nrows) ? row : (nrows - 1);  // clamp; no early exit

    // ---- load truth table row, convert to polar +-1 ----
    float v[64];
    const int4* t4 = reinterpret_cast<const int4*>(tt + (size_t)rowc * 64);
#pragma unroll
    for (int q = 0; q < 16; ++q) {
        int4 a = t4[q];
        v[4 * q + 0] = 1.0f - 2.0f * (float)a.x;
        v[4 * q + 1] = 1.0f - 2.0f * (float)a.y;
        v[4 * q + 2] = 1.0f - 2.0f * (float)a.z;
        v[4 * q + 3] = 1.0f - 2.0f * (float)a.w;
    }

    // ---- in-register FWHT (Sylvester order; == f @ H) ----
#pragma unroll
    for (int h = 1; h < 64; h <<= 1) {
#pragma unroll
        for (int i = 0; i < 64; ++i) {
            if ((i & h) == 0) {
                float a = v[i], b = v[i | h];
                v[i] = a + b;
                v[i | h] = a - b;
            }
        }
    }

    const float inv_n = 1.0f / 64.0f;
    float f[33];
    f[0] = v[0] * inv_n;  f[1] = v[1] * inv_n;  f[2] = v[2] * inv_n;
    f[3] = v[4] * inv_n;  f[4] = v[8] * inv_n;  f[5] = v[16] * inv_n;
    f[6] = v[32] * inv_n; f[7] = v[63] * inv_n;

    // ---- abs in place + single fused stats pass (walsh vals are exact even
    // ints in [-64,64]; Parseval: sumsq == 4096 exactly -> l2 const) ----
    float sumabs = 0.f, maxab = 0.f, cnt_sp = 0.f, cnt_lg = 0.f;
    float sum_hw = 0.f, bent = 0.f, ent = 0.f;
#pragma unroll
    for (int i = 0; i < 64; ++i) {
        float a = fabsf(v[i]);
        v[i] = a;
        sumabs += a;
        maxab = fmaxf(maxab, a);
        cnt_sp += (a < 6.4f) ? 1.0f : 0.0f;
        sum_hw += (a < 6.4f) ? 0.0f : (float)__popc(i);
        cnt_lg += (a > 32.0f) ? 1.0f : 0.0f;
        bent += fabsf(a - 8.0f);
        ent += entLUT[((int)a) >> 1];
    }

    f[8]  = cnt_sp * inv_n;
    f[9]  = maxab * inv_n;
    f[10] = sumabs * (1.0f / 4096.0f);
    f[11] = 0.015625f;  // l2 == 1/64 always (Parseval)
    f[12] = ent * 0.24044917348149316f;
    f[13] = (cnt_lg >= 0.5f && cnt_lg <= 2.5f) ? 1.0f : 0.0f;
    f[14] = fmaxf(0.0f, 0.5f - maxab * (1.0f / 128.0f)) * 2.0f;
    f[15] = sum_hw / (64.0f - cnt_sp + 1e-10f) * (1.0f / 6.0f);
    f[16] = (bent < 51.2f) ? 1.0f : 0.0f;

    // ---- top-16: Batcher-sort each 16-block desc + 3 bitonic top-merges ----
    {
        auto CE = [&](int u, int w2) {
            float x = v[u], y = v[w2];
            v[u] = fmaxf(x, y);
            v[w2] = fminf(x, y);
        };
#pragma unroll
        for (int b = 0; b < 4; ++b) {
            const int base = b * 16;
#pragma unroll
            for (int p = 1; p < 16; p <<= 1) {
#pragma unroll
                for (int k = p; k >= 1; k >>= 1) {
#pragma unroll
                    for (int j = k & (p - 1); j + k < 16; j += 2 * k) {
#pragma unroll
                        for (int i = 0; i < k; ++i) {
                            if (i + j + k < 16) {
                                if ((i + j) / (2 * p) == (i + j + k) / (2 * p))
                                    CE(base + i + j, base + i + j + k);
                            }
                        }
                    }
                }
            }
        }
        auto MERGE = [&](int a0, int b0) {
#pragma unroll
            for (int i = 0; i < 16; ++i)
                v[a0 + i] = fmaxf(v[a0 + i], v[b0 + 15 - i]);
#pragma unroll
            for (int d = 8; d >= 1; d >>= 1) {
#pragma unroll
                for (int i = 0; i < 16; ++i) {
                    if ((i & d) == 0) CE(a0 + i, a0 + i + d);
                }
            }
        };
        MERGE(0, 16);
        MERGE(32, 48);
        MERGE(0, 32);
    }
#pragma unroll
    for (int t = 0; t < 16; ++t) f[17 + t] = v[t] * inv_n;

    // ================= MLP via MFMA =================
    const int w = tid >> 6, l = tid & 63;
    _Float16* actB = &sAct[w][0][0];

    // pack features (f16) into act row l (swizzled), zero-padded to K=64
#pragma unroll
    for (int q = 0; q < 8; ++q) {
        half8 p;
#pragma unroll
        for (int e = 0; e < 8; ++e) {
            const int k = q * 8 + e;
            p[e] = (k < 33) ? (_Float16)f[k] : (_Float16)0.0f;
        }
        *(half8*)&actB[swz(l, q * 8)] = p;
    }
    asm volatile("s_waitcnt lgkmcnt(0)" ::: "memory");

    const int rowbase = blockIdx.x * TPB + w * 64;
    mfma_layer<false>(actB, wsW,         sP + 256, sP + 0,   sP + 64,
                      nullptr, 0, 0);
    mfma_layer<false>(actB, wsW + 8192,  sP + 320, sP + 128, sP + 192,
                      nullptr, 0, 0);
    mfma_layer<true >(actB, wsW + 16384, sP + 384, nullptr,  nullptr,
                      out, rowbase, nrows);
}

extern "C" void kernel_launch(void* const* d_in, const int* in_sizes, int n_in,
                              void* d_out, int out_size, void* d_ws, size_t ws_size,
                              hipStream_t stream) {
    const int*   tt  = (const int*)d_in[0];
    // d_in[1] is the Hadamard matrix H -- unused (in-register FWHT)
    const float* W1  = (const float*)d_in[2];
    const float* b1  = (const float*)d_in[3];
    const float* g1  = (const float*)d_in[4];
    const float* be1 = (const float*)d_in[5];
    const float* W2  = (const float*)d_in[6];
    const float* b2  = (const float*)d_in[7];
    const float* g2  = (const float*)d_in[8];
    const float* be2 = (const float*)d_in[9];
    const float* W3  = (const float*)d_in[10];
    const float* b3  = (const float*)d_in[11];
    float* out = (float*)d_out;
    _Float16* wsW = (_Float16*)d_ws;   // 48KB fragment-ordered hi/lo weights

    const int nrows = in_sizes[0] / 64;

    // stage weights into fragment order (tiny; runs in-stream each call)
    hipLaunchKernelGGL(weight_stage_kernel, dim3(48), dim3(256), 0, stream,
                       W1, W2, W3, wsW);

    const int grid = (nrows + TPB - 1) / TPB;
    hipLaunchKernelGGL(walsh_mlp_kernel, dim3(grid), dim3(TPB), 0, stream,
                       tt, b1, g1, be1, b2, g2, be2, b3, wsW, out, nrows);
}

// Round 5
// 124.678 us; speedup vs baseline: 2.3356x; 2.3356x over previous
//
#include <hip/hip_runtime.h>
#include <math.h>

#define TPB 256

typedef _Float16 half8 __attribute__((ext_vector_type(8)));
typedef float f32x4 __attribute__((ext_vector_type(4)));

// ---- XOR swizzle for the [64][64] f16 act tile (row = 128B = 32 banks).
// 16B chunk index c = col>>3 gets c ^= (row&7): A-fragment reads (16 lanes,
// same chunk col, 16 different rows) go from 16-way bank conflict to 2-way.
// Verified: SQ_LDS_BANK_CONFLICT 1.285e7 -> 0 (round 4).
__device__ __forceinline__ int swz(int row, int col) {
    return row * 64 + ((((col >> 3) ^ row) & 7) << 3) + (col & 7);
}

// Branchless GELU via Abramowitz-Stegun 7.1.26 erf (|abs err| <= 1.5e-7).
__device__ __forceinline__ float gelu_fast(float t) {
    float z = t * 0.70710678118654752440f;     // t / sqrt(2)
    float a = fabsf(z);
    float tau = __builtin_amdgcn_rcpf(fmaf(0.3275911f, a, 1.0f)); // 1/(1+p*a)
    float poly = fmaf(1.061405429f, tau, -1.453152027f);
    poly = fmaf(poly, tau, 1.421413741f);
    poly = fmaf(poly, tau, -0.284496736f);
    poly = fmaf(poly, tau, 0.254829592f);
    poly = poly * tau;
    float e = __expf(-a * a);                  // v_exp_f32
    float erf_a = fmaf(-poly, e, 1.0f);        // erf(|z|)
    float erf_z = copysignf(erf_a, z);
    return 0.5f * t * (1.0f + erf_z);
}

// ---- setup kernel: build fragment-ordered f16 hi/lo weights in workspace.
// Layout: half8 frag[L][nt][s][hl][lane]  (3*4*2*2*64 half8 = 48KB).
// Main-kernel B-load is then one perfectly-coalesced global_load_dwordx4 per
// (nt,s,hl): lane l reads frag[...][l]. Same 48KB for every block -> L1/L2
// resident broadcast; frees 48KB of LDS -> 4 blocks/CU instead of 1.
__global__ void weight_stage_kernel(const float* __restrict__ W1,
                                    const float* __restrict__ W2,
                                    const float* __restrict__ W3,
                                    _Float16* __restrict__ wsW) {
    const int idx = blockIdx.x * 256 + threadIdx.x;  // 12288 (L,nt,s,lane,e)
    if (idx >= 3 * 4 * 2 * 64 * 8) return;
    const int e    = idx & 7;
    const int lane = (idx >> 3) & 63;
    const int s    = (idx >> 9) & 1;
    const int nt   = (idx >> 10) & 3;
    const int L    = idx >> 12;
    const int g = lane >> 4, i = lane & 15;
    const int k = 32 * s + 8 * g + e;     // K index this slot consumes
    const int n = 16 * nt + i;            // N index this lane owns
    const float* W = (L == 0) ? W1 : (L == 1) ? W2 : W3;
    const int K = (L == 0) ? 33 : 64;
    const float val = (k < K) ? W[k * 64 + n] : 0.0f;  // W is [k][n]
    const _Float16 hi = (_Float16)val;
    const size_t base = ((((size_t)L * 4 + nt) * 2 + s) * 2) * 512
                        + (size_t)lane * 8 + e;
    wsW[base]       = hi;                              // hl=0
    wsW[base + 512] = (_Float16)(val - (float)hi);     // hl=1
}

// One MLP layer on a wave's 64x64 tile via mfma_f32_16x16x32_f16.
// A/B K-slot mapping cancels (HW pairs A-slot(g,e) with B-slot(g,e)); only
// the C/D map (col=lane&15, row=(lane>>4)*4+reg -- HW-verified) is relied on.
// Weights f16 hi+lo split (exact to ~2^-22). B-fragments come straight from
// the fragment-ordered global buffer (L1-hot). LN on f32 D fragments via
// shfl_xor over the 16-lane group.
template<bool LAST>
__device__ __forceinline__ void mfma_layer(
    _Float16* actB,                       // this wave's swizzled 64x64 tile
    const _Float16* __restrict__ wsL,     // frag[nt][s][hl][lane] for layer
    const float* bias, const float* gg, const float* bb,
    float* outp, int rowbase, int nrows)
{
    const int l = threadIdx.x & 63;
    const int g = l >> 4, i = l & 15;

    // B fragments: coalesced half8 loads, reused across all 4 M-tiles.
    const half8* Bp = reinterpret_cast<const half8*>(wsL);
    half8 Bh[4][2], Bl[4][2];
#pragma unroll
    for (int nt = 0; nt < 4; ++nt) {
#pragma unroll
        for (int s = 0; s < 2; ++s) {
            Bh[nt][s] = Bp[((nt * 2 + s) * 2 + 0) * 64 + l];
            Bl[nt][s] = Bp[((nt * 2 + s) * 2 + 1) * 64 + l];
        }
    }
    float bv[4], gv[4], bev[4];
#pragma unroll
    for (int nt = 0; nt < 4; ++nt) {
        bv[nt] = bias[16 * nt + i];
        if (!LAST) { gv[nt] = gg[16 * nt + i]; bev[nt] = bb[16 * nt + i]; }
    }
    const bool full = LAST && (rowbase + 63 < nrows);

#pragma unroll
    for (int t = 0; t < 4; ++t) {
        // A fragments for M-tile t (rows 16t..16t+15), K-steps 0,1 (swizzled)
        const half8 A0 = *(const half8*)&actB[swz(16 * t + i, 8 * g)];
        const half8 A1 = *(const half8*)&actB[swz(16 * t + i, 32 + 8 * g)];
        f32x4 D[4];
#pragma unroll
        for (int nt = 0; nt < 4; ++nt) {
            f32x4 d = {bv[nt], bv[nt], bv[nt], bv[nt]};
            d = __builtin_amdgcn_mfma_f32_16x16x32_f16(A0, Bh[nt][0], d, 0, 0, 0);
            d = __builtin_amdgcn_mfma_f32_16x16x32_f16(A1, Bh[nt][1], d, 0, 0, 0);
            d = __builtin_amdgcn_mfma_f32_16x16x32_f16(A0, Bl[nt][0], d, 0, 0, 0);
            d = __builtin_amdgcn_mfma_f32_16x16x32_f16(A1, Bl[nt][1], d, 0, 0, 0);
            D[nt] = d;
        }
        if (LAST) {
            // Store D fragments to global: row=16t+4g+reg, col=16nt+i
#pragma unroll
            for (int nt = 0; nt < 4; ++nt) {
#pragma unroll
                for (int r = 0; r < 4; ++r) {
                    const int grow = rowbase + 16 * t + 4 * g + r;
                    if (full || grow < nrows)
                        outp[(size_t)grow * 64 + 16 * nt + i] = D[nt][r];
                }
            }
        } else {
            // LN over the row's 64 values: per-lane N-tile partials (per
            // reg=row) + shfl_xor reduce across the 16 lanes of this group.
            f32x4 s4 = (D[0] + D[1]) + (D[2] + D[3]);
#pragma unroll
            for (int m = 1; m < 16; m <<= 1) {
                f32x4 o;
                o[0] = __shfl_xor(s4[0], m);
                o[1] = __shfl_xor(s4[1], m);
                o[2] = __shfl_xor(s4[2], m);
                o[3] = __shfl_xor(s4[3], m);
                s4 += o;
            }
            const f32x4 mean = s4 * 0.015625f;
            f32x4 vv = {0.f, 0.f, 0.f, 0.f};
#pragma unroll
            for (int nt = 0; nt < 4; ++nt) {
                f32x4 dd = D[nt] - mean;
                vv += dd * dd;
            }
#pragma unroll
            for (int m = 1; m < 16; m <<= 1) {
                f32x4 o;
                o[0] = __shfl_xor(vv[0], m);
                o[1] = __shfl_xor(vv[1], m);
                o[2] = __shfl_xor(vv[2], m);
                o[3] = __shfl_xor(vv[3], m);
                vv += o;
            }
            f32x4 rstd;
#pragma unroll
            for (int r = 0; r < 4; ++r)
                rstd[r] = rsqrtf(vv[r] * 0.015625f + 1e-5f);
            // normalize + GELU + write back transposed (swizzled, f16).
            // Tile t's output rows [16t,16t+16) are exactly the rows this
            // iteration already consumed -> no intra-layer hazard.
#pragma unroll
            for (int nt = 0; nt < 4; ++nt) {
#pragma unroll
                for (int r = 0; r < 4; ++r) {
                    float xx = (D[nt][r] - mean[r]) * rstd[r] * gv[nt] + bev[nt];
                    actB[swz(16 * t + 4 * g + r, 16 * nt + i)] =
                        (_Float16)gelu_fast(xx);
                }
            }
        }
    }
    if (!LAST) asm volatile("s_waitcnt lgkmcnt(0)" ::: "memory");
}

// hipcc empirical rule (4 data points, rounds 1-4): VGPR cap = 256 / arg2,
// INDEPENDENT of block size.  (256,4) forced VGPR=64 -> spill (round 4).
// (256,2): cap 128 = this kernel's natural allocation (round 3 compiled to
// exactly 128 uncapped).  Runtime residency: LDS 34KB -> 4 blocks/CU, and
// VGPR 128 -> 4 waves/SIMD -> 16 waves/CU (2x round 3).
__global__ __launch_bounds__(TPB, 2) void walsh_mlp_kernel(
    const int* __restrict__ tt,
    const float* __restrict__ b1,
    const float* __restrict__ g1, const float* __restrict__ be1,
    const float* __restrict__ b2,
    const float* __restrict__ g2, const float* __restrict__ be2,
    const float* __restrict__ b3,
    const _Float16* __restrict__ wsW,
    float* __restrict__ out, int nrows)
{
    __shared__ __align__(16) _Float16 sAct[4][64][64]; // per-wave act tiles
    __shared__ float sP[7 * 64];   // g1,be1,g2,be2,b1,b2,b3
    __shared__ float entLUT[33];   // -p*log(p+1e-10), p=(2i)^2/4096

    const int tid = threadIdx.x;
    if (tid < 64) {
        sP[tid]       = g1[tid];
        sP[64 + tid]  = be1[tid];
        sP[128 + tid] = g2[tid];
        sP[192 + tid] = be2[tid];
        sP[256 + tid] = b1[tid];
        sP[320 + tid] = b2[tid];
        sP[384 + tid] = b3[tid];
    }
    if (tid < 33) {
        const float a = 2.0f * (float)tid;
        const float p = (a * a) * 2.44140625e-4f;   // /4096 exact
        entLUT[tid] = -(p * __logf(p + 1e-10f));
    }
    __syncthreads();

    const int row = blockIdx.x * TPB + tid;
    const int rowc = (row < nrows) ? row : (nrows - 1);  // clamp; no early exit

    // ---- load truth table row, convert to polar +-1 ----
    float v[64];
    const int4* t4 = reinterpret_cast<const int4*>(tt + (size_t)rowc * 64);
#pragma unroll
    for (int q = 0; q < 16; ++q) {
        int4 a = t4[q];
        v[4 * q + 0] = 1.0f - 2.0f * (float)a.x;
        v[4 * q + 1] = 1.0f - 2.0f * (float)a.y;
        v[4 * q + 2] = 1.0f - 2.0f * (float)a.z;
        v[4 * q + 3] = 1.0f - 2.0f * (float)a.w;
    }

    // ---- in-register FWHT (Sylvester order; == f @ H) ----
#pragma unroll
    for (int h = 1; h < 64; h <<= 1) {
#pragma unroll
        for (int i = 0; i < 64; ++i) {
            if ((i & h) == 0) {
                float a = v[i], b = v[i | h];
                v[i] = a + b;
                v[i | h] = a - b;
            }
        }
    }

    const float inv_n = 1.0f / 64.0f;
    float f[33];
    f[0] = v[0] * inv_n;  f[1] = v[1] * inv_n;  f[2] = v[2] * inv_n;
    f[3] = v[4] * inv_n;  f[4] = v[8] * inv_n;  f[5] = v[16] * inv_n;
    f[6] = v[32] * inv_n; f[7] = v[63] * inv_n;

    // ---- abs in place + single fused stats pass (walsh vals are exact even
    // ints in [-64,64]; Parseval: sumsq == 4096 exactly -> l2 const) ----
    float sumabs = 0.f, maxab = 0.f, cnt_sp = 0.f, cnt_lg = 0.f;
    float sum_hw = 0.f, bent = 0.f, ent = 0.f;
#pragma unroll
    for (int i = 0; i < 64; ++i) {
        float a = fabsf(v[i]);
        v[i] = a;
        sumabs += a;
        maxab = fmaxf(maxab, a);
        cnt_sp += (a < 6.4f) ? 1.0f : 0.0f;
        sum_hw += (a < 6.4f) ? 0.0f : (float)__popc(i);
        cnt_lg += (a > 32.0f) ? 1.0f : 0.0f;
        bent += fabsf(a - 8.0f);
        ent += entLUT[((int)a) >> 1];
    }

    f[8]  = cnt_sp * inv_n;
    f[9]  = maxab * inv_n;
    f[10] = sumabs * (1.0f / 4096.0f);
    f[11] = 0.015625f;  // l2 == 1/64 always (Parseval)
    f[12] = ent * 0.24044917348149316f;
    f[13] = (cnt_lg >= 0.5f && cnt_lg <= 2.5f) ? 1.0f : 0.0f;
    f[14] = fmaxf(0.0f, 0.5f - maxab * (1.0f / 128.0f)) * 2.0f;
    f[15] = sum_hw / (64.0f - cnt_sp + 1e-10f) * (1.0f / 6.0f);
    f[16] = (bent < 51.2f) ? 1.0f : 0.0f;

    // ---- top-16: Batcher-sort each 16-block desc + 3 bitonic top-merges ----
    {
        auto CE = [&](int u, int w2) {
            float x = v[u], y = v[w2];
            v[u] = fmaxf(x, y);
            v[w2] = fminf(x, y);
        };
#pragma unroll
        for (int b = 0; b < 4; ++b) {
            const int base = b * 16;
#pragma unroll
            for (int p = 1; p < 16; p <<= 1) {
#pragma unroll
                for (int k = p; k >= 1; k >>= 1) {
#pragma unroll
                    for (int j = k & (p - 1); j + k < 16; j += 2 * k) {
#pragma unroll
                        for (int i = 0; i < k; ++i) {
                            if (i + j + k < 16) {
                                if ((i + j) / (2 * p) == (i + j + k) / (2 * p))
                                    CE(base + i + j, base + i + j + k);
                            }
                        }
                    }
                }
            }
        }
        auto MERGE = [&](int a0, int b0) {
#pragma unroll
            for (int i = 0; i < 16; ++i)
                v[a0 + i] = fmaxf(v[a0 + i], v[b0 + 15 - i]);
#pragma unroll
            for (int d = 8; d >= 1; d >>= 1) {
#pragma unroll
                for (int i = 0; i < 16; ++i) {
                    if ((i & d) == 0) CE(a0 + i, a0 + i + d);
                }
            }
        };
        MERGE(0, 16);
        MERGE(32, 48);
        MERGE(0, 32);
    }
#pragma unroll
    for (int t = 0; t < 16; ++t) f[17 + t] = v[t] * inv_n;

    // ================= MLP via MFMA =================
    const int w = tid >> 6, l = tid & 63;
    _Float16* actB = &sAct[w][0][0];

    // pack features (f16) into act row l (swizzled), zero-padded to K=64
#pragma unroll
    for (int q = 0; q < 8; ++q) {
        half8 p;
#pragma unroll
        for (int e = 0; e < 8; ++e) {
            const int k = q * 8 + e;
            p[e] = (k < 33) ? (_Float16)f[k] : (_Float16)0.0f;
        }
        *(half8*)&actB[swz(l, q * 8)] = p;
    }
    asm volatile("s_waitcnt lgkmcnt(0)" ::: "memory");

    const int rowbase = blockIdx.x * TPB + w * 64;
    mfma_layer<false>(actB, wsW,         sP + 256, sP + 0,   sP + 64,
                      nullptr, 0, 0);
    mfma_layer<false>(actB, wsW + 8192,  sP + 320, sP + 128, sP + 192,
                      nullptr, 0, 0);
    mfma_layer<true >(actB, wsW + 16384, sP + 384, nullptr,  nullptr,
                      out, rowbase, nrows);
}

extern "C" void kernel_launch(void* const* d_in, const int* in_sizes, int n_in,
                              void* d_out, int out_size, void* d_ws, size_t ws_size,
                              hipStream_t stream) {
    const int*   tt  = (const int*)d_in[0];
    // d_in[1] is the Hadamard matrix H -- unused (in-register FWHT)
    const float* W1  = (const float*)d_in[2];
    const float* b1  = (const float*)d_in[3];
    const float* g1  = (const float*)d_in[4];
    const float* be1 = (const float*)d_in[5];
    const float* W2  = (const float*)d_in[6];
    const float* b2  = (const float*)d_in[7];
    const float* g2  = (const float*)d_in[8];
    const float* be2 = (const float*)d_in[9];
    const float* W3  = (const float*)d_in[10];
    const float* b3  = (const float*)d_in[11];
    float* out = (float*)d_out;
    _Float16* wsW = (_Float16*)d_ws;   // 48KB fragment-ordered hi/lo weights

    const int nrows = in_sizes[0] / 64;

    // stage weights into fragment order (tiny; runs in-stream each call)
    hipLaunchKernelGGL(weight_stage_kernel, dim3(48), dim3(256), 0, stream,
                       W1, W2, W3, wsW);

    const int grid = (nrows + TPB - 1) / TPB;
    hipLaunchKernelGGL(walsh_mlp_kernel, dim3(grid), dim3(TPB), 0, stream,
                       tt, b1, g1, be1, b2, g2, be2, b3, wsW, out, nrows);
}

// Round 7
// 119.955 us; speedup vs baseline: 2.4276x; 1.0394x over previous
//
#include <hip/hip_runtime.h>
#include <math.h>

#define TPB 256

typedef _Float16 half8 __attribute__((ext_vector_type(8)));
typedef float f32x4 __attribute__((ext_vector_type(4)));

// ---- XOR swizzle for the [64][64] f16 act tile (row = 128B = 32 banks).
// 16B chunk index c = col>>3 gets c ^= (row&7): A-fragment reads (16 lanes,
// same chunk col, 16 different rows) go from 16-way bank conflict to 2-way.
// Verified: SQ_LDS_BANK_CONFLICT 1.285e7 -> 0 (round 4).
__device__ __forceinline__ int swz(int row, int col) {
    return row * 64 + ((((col >> 3) ^ row) & 7) << 3) + (col & 7);
}

// Branchless GELU via Abramowitz-Stegun 7.1.26 erf (|abs err| <= 1.5e-7).
__device__ __forceinline__ float gelu_fast(float t) {
    float z = t * 0.70710678118654752440f;     // t / sqrt(2)
    float a = fabsf(z);
    float tau = __builtin_amdgcn_rcpf(fmaf(0.3275911f, a, 1.0f)); // 1/(1+p*a)
    float poly = fmaf(1.061405429f, tau, -1.453152027f);
    poly = fmaf(poly, tau, 1.421413741f);
    poly = fmaf(poly, tau, -0.284496736f);
    poly = fmaf(poly, tau, 0.254829592f);
    poly = poly * tau;
    float e = __expf(-a * a);                  // v_exp_f32
    float erf_a = fmaf(-poly, e, 1.0f);        // erf(|z|)
    float erf_z = copysignf(erf_a, z);
    return 0.5f * t * (1.0f + erf_z);
}

// DPP row_ror sum-reduce step: x += ror_within_16_lane_row(x, N).
// Rotations by 1,2,4,8 give every lane the full 16-lane sum. VALU pipe --
// replaces __shfl_xor (ds_bpermute = LDS pipe, ~100cy serial round trips).
template<int CTRL>
__device__ __forceinline__ f32x4 dpp_add4(f32x4 x) {
#pragma unroll
    for (int r = 0; r < 4; ++r) {
        int o = __builtin_amdgcn_update_dpp(0, __float_as_int(x[r]),
                                            CTRL, 0xf, 0xf, false);
        x[r] += __int_as_float(o);
    }
    return x;
}
__device__ __forceinline__ f32x4 row_reduce16(f32x4 x) {
    x = dpp_add4<0x121>(x);   // row_ror:1
    x = dpp_add4<0x122>(x);   // row_ror:2
    x = dpp_add4<0x124>(x);   // row_ror:4
    x = dpp_add4<0x128>(x);   // row_ror:8
    return x;
}

// pack two f32 -> one u32 of 2 f16 (RTZ), in the builtin's native type.
__device__ __forceinline__ unsigned int pk_f16(float a, float b) {
    auto p = __builtin_amdgcn_cvt_pkrtz(a, b);   // __fp16 ext_vector(2)
    return __builtin_bit_cast(unsigned int, p);
}

// ---- setup kernel: build fragment-ordered f16 hi/lo weights in workspace.
// Layout: half8 frag[L][nt][s][hl][lane]  (3*4*2*2*64 half8 = 48KB).
// COLUMN-INTERLEAVED N mapping: tile nt, lane i owns weight col n = 4*i+nt,
// so a lane's 4 D values (nt=0..3) are 4 CONSECUTIVE output columns ->
// packed b64 LDS writebacks and float4 global stores in the main kernel.
__global__ void weight_stage_kernel(const float* __restrict__ W1,
                                    const float* __restrict__ W2,
                                    const float* __restrict__ W3,
                                    _Float16* __restrict__ wsW) {
    const int idx = blockIdx.x * 256 + threadIdx.x;  // 12288 (L,nt,s,lane,e)
    if (idx >= 3 * 4 * 2 * 64 * 8) return;
    const int e    = idx & 7;
    const int lane = (idx >> 3) & 63;
    const int s    = (idx >> 9) & 1;
    const int nt   = (idx >> 10) & 3;
    const int L    = idx >> 12;
    const int g = lane >> 4, i = lane & 15;
    const int k = 32 * s + 8 * g + e;     // K index this slot consumes
    const int n = 4 * i + nt;             // N index this lane owns (interleaved)
    const float* W = (L == 0) ? W1 : (L == 1) ? W2 : W3;
    const int K = (L == 0) ? 33 : 64;
    const float val = (k < K) ? W[k * 64 + n] : 0.0f;  // W is [k][n]
    const _Float16 hi = (_Float16)val;
    const size_t base = ((((size_t)L * 4 + nt) * 2 + s) * 2) * 512
                        + (size_t)lane * 8 + e;
    wsW[base]       = hi;                              // hl=0
    wsW[base + 512] = (_Float16)(val - (float)hi);     // hl=1
}

// One MLP layer on a wave's 64x64 tile via mfma_f32_16x16x32_f16.
// A/B K-slot mapping cancels (HW pairs A-slot(g,e) with B-slot(g,e)); only
// the C/D map (col=lane&15, row=(lane>>4)*4+reg -- HW-verified) is relied on.
// Weights f16 hi+lo split (exact to ~2^-22). B-fragments from the
// fragment-ordered global buffer (L1-hot). LN on f32 D fragments via DPP
// row-reduce (fused mean+var: E[x^2]-m^2, single pass, no LDS).
template<bool LAST>
__device__ __forceinline__ void mfma_layer(
    _Float16* actB,                       // this wave's swizzled 64x64 tile
    const _Float16* __restrict__ wsL,     // frag[nt][s][hl][lane] for layer
    const float* bias, const float* gg, const float* bb,
    float* outp, int rowbase, int nrows)
{
    const int l = threadIdx.x & 63;
    const int g = l >> 4, i = l & 15;

    // B fragments: coalesced half8 loads, reused across all 4 M-tiles.
    const half8* Bp = reinterpret_cast<const half8*>(wsL);
    half8 Bh[4][2], Bl[4][2];
#pragma unroll
    for (int nt = 0; nt < 4; ++nt) {
#pragma unroll
        for (int s = 0; s < 2; ++s) {
            Bh[nt][s] = Bp[((nt * 2 + s) * 2 + 0) * 64 + l];
            Bl[nt][s] = Bp[((nt * 2 + s) * 2 + 1) * 64 + l];
        }
    }
    // per-lane params: cols 4i..4i+3 -> single float4 loads
    const f32x4 bvv = *(const f32x4*)&bias[4 * i];
    f32x4 gvv, bevv;
    if (!LAST) {
        gvv  = *(const f32x4*)&gg[4 * i];
        bevv = *(const f32x4*)&bb[4 * i];
    }
    const bool full = LAST && (rowbase + 63 < nrows);

#pragma unroll
    for (int t = 0; t < 4; ++t) {
        // A fragments for M-tile t (rows 16t..16t+15), K-steps 0,1 (swizzled)
        const half8 A0 = *(const half8*)&actB[swz(16 * t + i, 8 * g)];
        const half8 A1 = *(const half8*)&actB[swz(16 * t + i, 32 + 8 * g)];
        f32x4 D[4];
#pragma unroll
        for (int nt = 0; nt < 4; ++nt) {
            f32x4 d = {bvv[nt], bvv[nt], bvv[nt], bvv[nt]};
            d = __builtin_amdgcn_mfma_f32_16x16x32_f16(A0, Bh[nt][0], d, 0, 0, 0);
            d = __builtin_amdgcn_mfma_f32_16x16x32_f16(A1, Bh[nt][1], d, 0, 0, 0);
            d = __builtin_amdgcn_mfma_f32_16x16x32_f16(A0, Bl[nt][0], d, 0, 0, 0);
            d = __builtin_amdgcn_mfma_f32_16x16x32_f16(A1, Bl[nt][1], d, 0, 0, 0);
            D[nt] = d;
        }
        if (LAST) {
            // row = 16t+4g+r, this lane's cols = [4i, 4i+4) -> float4 store
#pragma unroll
            for (int r = 0; r < 4; ++r) {
                const int grow = rowbase + 16 * t + 4 * g + r;
                if (full || grow < nrows) {
                    f32x4 st = {D[0][r], D[1][r], D[2][r], D[3][r]};
                    *reinterpret_cast<f32x4*>(&outp[(size_t)grow * 64 + 4 * i]) = st;
                }
            }
        } else {
            // fused mean+var: reduce (sum, sumsq) across the 16-lane group
            // in ONE DPP pass (no LDS, no serial mean->var dependency).
            f32x4 s4 = (D[0] + D[1]) + (D[2] + D[3]);
            f32x4 q4 = D[0] * D[0];
            q4 = D[1] * D[1] + q4;
            q4 = D[2] * D[2] + q4;
            q4 = D[3] * D[3] + q4;
            s4 = row_reduce16(s4);
            q4 = row_reduce16(q4);
            f32x4 mean = s4 * 0.015625f;
            f32x4 rstd;
#pragma unroll
            for (int r = 0; r < 4; ++r) {
                float var = q4[r] * 0.015625f - mean[r] * mean[r];
                rstd[r] = rsqrtf(var + 1e-5f);
            }
            // normalize + GELU + packed b64 writeback (cols 4i..4i+3 of
            // row 16t+4g+r). Tile t's output rows [16t,16t+16) are exactly
            // the rows this iteration already consumed -> no hazard.
#pragma unroll
            for (int r = 0; r < 4; ++r) {
                float x0 = (D[0][r] - mean[r]) * rstd[r] * gvv[0] + bevv[0];
                float x1 = (D[1][r] - mean[r]) * rstd[r] * gvv[1] + bevv[1];
                float x2 = (D[2][r] - mean[r]) * rstd[r] * gvv[2] + bevv[2];
                float x3 = (D[3][r] - mean[r]) * rstd[r] * gvv[3] + bevv[3];
                uint2 st;
                st.x = pk_f16(gelu_fast(x0), gelu_fast(x1));
                st.y = pk_f16(gelu_fast(x2), gelu_fast(x3));
                *reinterpret_cast<uint2*>(
                    &actB[swz(16 * t + 4 * g + r, 4 * i)]) = st;
            }
        }
    }
    if (!LAST) asm volatile("s_waitcnt lgkmcnt(0)" ::: "memory");
}

// hipcc empirical rule (rounds 1-5): VGPR cap = 256/arg2, independent of
// block size. (256,2): cap 128 >= natural ~124 -> no spill. Residency:
// LDS 34KB -> 4 blocks/CU, VGPR 124 -> 4 waves/SIMD -> 16 waves/CU.
__global__ __launch_bounds__(TPB, 2) void walsh_mlp_kernel(
    const int* __restrict__ tt,
    const float* __restrict__ b1,
    const float* __restrict__ g1, const float* __restrict__ be1,
    const float* __restrict__ b2,
    const float* __restrict__ g2, const float* __restrict__ be2,
    const float* __restrict__ b3,
    const _Float16* __restrict__ wsW,
    float* __restrict__ out, int nrows)
{
    __shared__ __align__(16) _Float16 sAct[4][64][64]; // per-wave act tiles
    __shared__ float sP[7 * 64];   // g1,be1,g2,be2,b1,b2,b3
    __shared__ float entLUT[33];   // -p*log(p+1e-10), p=(2i)^2/4096

    const int tid = threadIdx.x;
    if (tid < 64) {
        sP[tid]       = g1[tid];
        sP[64 + tid]  = be1[tid];
        sP[128 + tid] = g2[tid];
        sP[192 + tid] = be2[tid];
        sP[256 + tid] = b1[tid];
        sP[320 + tid] = b2[tid];
        sP[384 + tid] = b3[tid];
    }
    if (tid < 33) {
        const float a = 2.0f * (float)tid;
        const float p = (a * a) * 2.44140625e-4f;   // /4096 exact
        entLUT[tid] = -(p * __logf(p + 1e-10f));
    }
    __syncthreads();

    const int row = blockIdx.x * TPB + tid;
    const int rowc = (row < nrows) ? row : (nrows - 1);  // clamp; no early exit

    // ---- load truth table row, convert to polar +-1 ----
    float v[64];
    const int4* t4 = reinterpret_cast<const int4*>(tt + (size_t)rowc * 64);
#pragma unroll
    for (int q = 0; q < 16; ++q) {
        int4 a = t4[q];
        v[4 * q + 0] = 1.0f - 2.0f * (float)a.x;
        v[4 * q + 1] = 1.0f - 2.0f * (float)a.y;
        v[4 * q + 2] = 1.0f - 2.0f * (float)a.z;
        v[4 * q + 3] = 1.0f - 2.0f * (float)a.w;
    }

    // ---- in-register FWHT (Sylvester order; == f @ H) ----
#pragma unroll
    for (int h = 1; h < 64; h <<= 1) {
#pragma unroll
        for (int i = 0; i < 64; ++i) {
            if ((i & h) == 0) {
                float a = v[i], b = v[i | h];
                v[i] = a + b;
                v[i | h] = a - b;
            }
        }
    }

    const float inv_n = 1.0f / 64.0f;
    float f[33];
    f[0] = v[0] * inv_n;  f[1] = v[1] * inv_n;  f[2] = v[2] * inv_n;
    f[3] = v[4] * inv_n;  f[4] = v[8] * inv_n;  f[5] = v[16] * inv_n;
    f[6] = v[32] * inv_n; f[7] = v[63] * inv_n;

    // ---- abs in place + single fused stats pass (walsh vals are exact even
    // ints in [-64,64]; Parseval: sumsq == 4096 exactly -> l2 const) ----
    float sumabs = 0.f, maxab = 0.f, cnt_sp = 0.f, cnt_lg = 0.f;
    float sum_hw = 0.f, bent = 0.f, ent = 0.f;
#pragma unroll
    for (int i = 0; i < 64; ++i) {
        float a = fabsf(v[i]);
        v[i] = a;
        sumabs += a;
        maxab = fmaxf(maxab, a);
        cnt_sp += (a < 6.4f) ? 1.0f : 0.0f;
        sum_hw += (a < 6.4f) ? 0.0f : (float)__popc(i);
        cnt_lg += (a > 32.0f) ? 1.0f : 0.0f;
        bent += fabsf(a - 8.0f);
        ent += entLUT[((int)a) >> 1];
    }

    f[8]  = cnt_sp * inv_n;
    f[9]  = maxab * inv_n;
    f[10] = sumabs * (1.0f / 4096.0f);
    f[11] = 0.015625f;  // l2 == 1/64 always (Parseval)
    f[12] = ent * 0.24044917348149316f;
    f[13] = (cnt_lg >= 0.5f && cnt_lg <= 2.5f) ? 1.0f : 0.0f;
    f[14] = fmaxf(0.0f, 0.5f - maxab * (1.0f / 128.0f)) * 2.0f;
    f[15] = sum_hw / (64.0f - cnt_sp + 1e-10f) * (1.0f / 6.0f);
    f[16] = (bent < 51.2f) ? 1.0f : 0.0f;

    // ---- top-16: Batcher-sort each 16-block desc + 3 bitonic top-merges ----
    {
        auto CE = [&](int u, int w2) {
            float x = v[u], y = v[w2];
            v[u] = fmaxf(x, y);
            v[w2] = fminf(x, y);
        };
#pragma unroll
        for (int b = 0; b < 4; ++b) {
            const int base = b * 16;
#pragma unroll
            for (int p = 1; p < 16; p <<= 1) {
#pragma unroll
                for (int k = p; k >= 1; k >>= 1) {
#pragma unroll
                    for (int j = k & (p - 1); j + k < 16; j += 2 * k) {
#pragma unroll
                        for (int i = 0; i < k; ++i) {
                            if (i + j + k < 16) {
                                if ((i + j) / (2 * p) == (i + j + k) / (2 * p))
                                    CE(base + i + j, base + i + j + k);
                            }
                        }
                    }
                }
            }
        }
        auto MERGE = [&](int a0, int b0) {
#pragma unroll
            for (int i = 0; i < 16; ++i)
                v[a0 + i] = fmaxf(v[a0 + i], v[b0 + 15 - i]);
#pragma unroll
            for (int d = 8; d >= 1; d >>= 1) {
#pragma unroll
                for (int i = 0; i < 16; ++i) {
                    if ((i & d) == 0) CE(a0 + i, a0 + i + d);
                }
            }
        };
        MERGE(0, 16);
        MERGE(32, 48);
        MERGE(0, 32);
    }
#pragma unroll
    for (int t = 0; t < 16; ++t) f[17 + t] = v[t] * inv_n;

    // ================= MLP via MFMA =================
    const int w = tid >> 6, l = tid & 63;
    _Float16* actB = &sAct[w][0][0];

    // pack features (f16) into act row l (swizzled), zero-padded to K=64
#pragma unroll
    for (int q = 0; q < 8; ++q) {
        half8 p;
#pragma unroll
        for (int e = 0; e < 8; ++e) {
            const int k = q * 8 + e;
            p[e] = (k < 33) ? (_Float16)f[k] : (_Float16)0.0f;
        }
        *(half8*)&actB[swz(l, q * 8)] = p;
    }
    asm volatile("s_waitcnt lgkmcnt(0)" ::: "memory");

    const int rowbase = blockIdx.x * TPB + w * 64;
    mfma_layer<false>(actB, wsW,         sP + 256, sP + 0,   sP + 64,
                      nullptr, 0, 0);
    mfma_layer<false>(actB, wsW + 8192,  sP + 320, sP + 128, sP + 192,
                      nullptr, 0, 0);
    mfma_layer<true >(actB, wsW + 16384, sP + 384, nullptr,  nullptr,
                      out, rowbase, nrows);
}

extern "C" void kernel_launch(void* const* d_in, const int* in_sizes, int n_in,
                              void* d_out, int out_size, void* d_ws, size_t ws_size,
                              hipStream_t stream) {
    const int*   tt  = (const int*)d_in[0];
    // d_in[1] is the Hadamard matrix H -- unused (in-register FWHT)
    const float* W1  = (const float*)d_in[2];
    const float* b1  = (const float*)d_in[3];
    const float* g1  = (const float*)d_in[4];
    const float* be1 = (const float*)d_in[5];
    const float* W2  = (const float*)d_in[6];
    const float* b2  = (const float*)d_in[7];
    const float* g2  = (const float*)d_in[8];
    const float* be2 = (const float*)d_in[9];
    const float* W3  = (const float*)d_in[10];
    const float* b3  = (const float*)d_in[11];
    float* out = (float*)d_out;
    _Float16* wsW = (_Float16*)d_ws;   // 48KB fragment-ordered hi/lo weights

    const int nrows = in_sizes[0] / 64;

    // stage weights into fragment order (tiny; runs in-stream each call)
    hipLaunchKernelGGL(weight_stage_kernel, dim3(48), dim3(256), 0, stream,
                       W1, W2, W3, wsW);

    const int grid = (nrows + TPB - 1) / TPB;
    hipLaunchKernelGGL(walsh_mlp_kernel, dim3(grid), dim3(TPB), 0, stream,
                       tt, b1, g1, be1, b2, g2, be2, b3, wsW, out, nrows);
}

// Round 9
// 92.083 us; speedup vs baseline: 3.1624x; 1.3027x over previous
//
#include <hip/hip_runtime.h>
#include <math.h>

#define TPB 256

typedef _Float16 half8 __attribute__((ext_vector_type(8)));
typedef _Float16 h2 __attribute__((ext_vector_type(2)));
typedef float f32x4 __attribute__((ext_vector_type(4)));

// ---- XOR swizzle for the [64][64] f16 act tile (row = 128B = 32 banks).
// Verified: SQ_LDS_BANK_CONFLICT 1.285e7 -> 0 (round 4).
__device__ __forceinline__ int swz(int row, int col) {
    return row * 64 + ((((col >> 3) ^ row) & 7) << 3) + (col & 7);
}

// pack two f32 -> one u32 of 2 f16 (RTZ; exact for the small ints we pack).
__device__ __forceinline__ unsigned int pk_f16(float a, float b) {
    auto p = __builtin_amdgcn_cvt_pkrtz(a, b);   // __fp16 ext_vector(2)
    return __builtin_bit_cast(unsigned int, p);
}

// f32 sigmoid-form GELU (tanh approximation):
//   gelu(x) ~= x * sigmoid(x*(1.5957691 + 0.07135481*x^2))
// ~8 VALU ops vs ~16 for the erf form. Systematic err <= ~1e-3 (folded
// under the f16 act-tile rounding). No fp16 header dependence.
__device__ __forceinline__ float gelu_sig(float x) {
    float u = x * fmaf(0.0713548162f, x * x, 1.595769122f);  // 2u
    float e = __expf(-u);
    return x * __builtin_amdgcn_rcpf(1.0f + e);
}

// packed f16 compare-exchange (descending): exact for our even-int values.
// __builtin_elementwise_max/min lower to v_pk_max_f16 / v_pk_min_f16.
__device__ __forceinline__ void ce2(h2& x, h2& y) {
    h2 mx = __builtin_elementwise_max(x, y);
    h2 mn = __builtin_elementwise_min(x, y);
    x = mx; y = mn;
}

// DPP row_ror sum-reduce: rotations by 1,2,4,8 within the 16-lane row give
// every lane the full 16-lane sum. VALU pipe (no LDS round trips).
template<int CTRL>
__device__ __forceinline__ f32x4 dpp_add4(f32x4 x) {
#pragma unroll
    for (int r = 0; r < 4; ++r) {
        int o = __builtin_amdgcn_update_dpp(0, __float_as_int(x[r]),
                                            CTRL, 0xf, 0xf, false);
        x[r] += __int_as_float(o);
    }
    return x;
}
__device__ __forceinline__ f32x4 row_reduce16(f32x4 x) {
    x = dpp_add4<0x121>(x);   // row_ror:1
    x = dpp_add4<0x122>(x);   // row_ror:2
    x = dpp_add4<0x124>(x);   // row_ror:4
    x = dpp_add4<0x128>(x);   // row_ror:8
    return x;
}

// ---- setup kernel: fragment-ordered f16 hi/lo weights in workspace.
// half8 frag[L][nt][s][hl][lane]; COLUMN-INTERLEAVED N: lane i owns col
// n = 4*i+nt -> a lane's 4 D values are 4 consecutive output columns.
__global__ void weight_stage_kernel(const float* __restrict__ W1,
                                    const float* __restrict__ W2,
                                    const float* __restrict__ W3,
                                    _Float16* __restrict__ wsW) {
    const int idx = blockIdx.x * 256 + threadIdx.x;  // 12288 (L,nt,s,lane,e)
    if (idx >= 3 * 4 * 2 * 64 * 8) return;
    const int e    = idx & 7;
    const int lane = (idx >> 3) & 63;
    const int s    = (idx >> 9) & 1;
    const int nt   = (idx >> 10) & 3;
    const int L    = idx >> 12;
    const int g = lane >> 4, i = lane & 15;
    const int k = 32 * s + 8 * g + e;     // K index this slot consumes
    const int n = 4 * i + nt;             // N index this lane owns (interleaved)
    const float* W = (L == 0) ? W1 : (L == 1) ? W2 : W3;
    const int K = (L == 0) ? 33 : 64;
    const float val = (k < K) ? W[k * 64 + n] : 0.0f;  // W is [k][n]
    const _Float16 hi = (_Float16)val;
    const size_t base = ((((size_t)L * 4 + nt) * 2 + s) * 2) * 512
                        + (size_t)lane * 8 + e;
    wsW[base]       = hi;                              // hl=0
    wsW[base + 512] = (_Float16)(val - (float)hi);     // hl=1
}

// One MLP layer on a wave's 64x64 tile via mfma_f32_16x16x32_f16.
// Weights f16 hi+lo split (exact to ~2^-22). LN on f32 D fragments via DPP
// row-reduce (fused mean+var).
template<bool LAST>
__device__ __forceinline__ void mfma_layer(
    _Float16* actB,                       // this wave's swizzled 64x64 tile
    const _Float16* __restrict__ wsL,     // frag[nt][s][hl][lane] for layer
    const float* bias, const float* gg, const float* bb,
    float* outp, int rowbase, int nrows)
{
    const int l = threadIdx.x & 63;
    const int g = l >> 4, i = l & 15;

    // B fragments: coalesced half8 loads, reused across all 4 M-tiles.
    const half8* Bp = reinterpret_cast<const half8*>(wsL);
    half8 Bh[4][2], Bl[4][2];
#pragma unroll
    for (int nt = 0; nt < 4; ++nt) {
#pragma unroll
        for (int s = 0; s < 2; ++s) {
            Bh[nt][s] = Bp[((nt * 2 + s) * 2 + 0) * 64 + l];
            Bl[nt][s] = Bp[((nt * 2 + s) * 2 + 1) * 64 + l];
        }
    }
    // per-lane params: cols 4i..4i+3 -> single float4 loads
    const f32x4 bvv = *(const f32x4*)&bias[4 * i];
    f32x4 gvv, bevv;
    if (!LAST) {
        gvv  = *(const f32x4*)&gg[4 * i];
        bevv = *(const f32x4*)&bb[4 * i];
    }
    const bool full = LAST && (rowbase + 63 < nrows);

#pragma unroll
    for (int t = 0; t < 4; ++t) {
        // A fragments for M-tile t (rows 16t..16t+15), K-steps 0,1 (swizzled)
        const half8 A0 = *(const half8*)&actB[swz(16 * t + i, 8 * g)];
        const half8 A1 = *(const half8*)&actB[swz(16 * t + i, 32 + 8 * g)];
        f32x4 D[4];
#pragma unroll
        for (int nt = 0; nt < 4; ++nt) {
            f32x4 d = {bvv[nt], bvv[nt], bvv[nt], bvv[nt]};
            d = __builtin_amdgcn_mfma_f32_16x16x32_f16(A0, Bh[nt][0], d, 0, 0, 0);
            d = __builtin_amdgcn_mfma_f32_16x16x32_f16(A1, Bh[nt][1], d, 0, 0, 0);
            d = __builtin_amdgcn_mfma_f32_16x16x32_f16(A0, Bl[nt][0], d, 0, 0, 0);
            d = __builtin_amdgcn_mfma_f32_16x16x32_f16(A1, Bl[nt][1], d, 0, 0, 0);
            D[nt] = d;
        }
        if (LAST) {
            // row = 16t+4g+r, this lane's cols = [4i, 4i+4) -> float4 store
#pragma unroll
            for (int r = 0; r < 4; ++r) {
                const int grow = rowbase + 16 * t + 4 * g + r;
                if (full || grow < nrows) {
                    f32x4 st = {D[0][r], D[1][r], D[2][r], D[3][r]};
                    *reinterpret_cast<f32x4*>(&outp[(size_t)grow * 64 + 4 * i]) = st;
                }
            }
        } else {
            // fused mean+var across the 16-lane group in one DPP pass.
            f32x4 s4 = (D[0] + D[1]) + (D[2] + D[3]);
            f32x4 q4 = D[0] * D[0];
            q4 = D[1] * D[1] + q4;
            q4 = D[2] * D[2] + q4;
            q4 = D[3] * D[3] + q4;
            s4 = row_reduce16(s4);
            q4 = row_reduce16(q4);
            f32x4 mean = s4 * 0.015625f;
            f32x4 rstd;
#pragma unroll
            for (int r = 0; r < 4; ++r) {
                float var = q4[r] * 0.015625f - mean[r] * mean[r];
                rstd[r] = rsqrtf(var + 1e-5f);
            }
            // normalize (f32) -> GELU (sigmoid form) -> pack f16 -> b64 write
#pragma unroll
            for (int r = 0; r < 4; ++r) {
                float x0 = (D[0][r] - mean[r]) * rstd[r] * gvv[0] + bevv[0];
                float x1 = (D[1][r] - mean[r]) * rstd[r] * gvv[1] + bevv[1];
                float x2 = (D[2][r] - mean[r]) * rstd[r] * gvv[2] + bevv[2];
                float x3 = (D[3][r] - mean[r]) * rstd[r] * gvv[3] + bevv[3];
                uint2 st;
                st.x = pk_f16(gelu_sig(x0), gelu_sig(x1));
                st.y = pk_f16(gelu_sig(x2), gelu_sig(x3));
                *reinterpret_cast<uint2*>(
                    &actB[swz(16 * t + 4 * g + r, 4 * i)]) = st;
            }
        }
    }
    if (!LAST) asm volatile("s_waitcnt lgkmcnt(0)" ::: "memory");
}

// hipcc empirical rule (rounds 1-5): VGPR cap = 256/arg2, independent of
// block size. (256,2): cap 128 >= natural (~92-124 in this family).
// Residency: LDS 34KB -> 4 blocks/CU; 16 waves/CU.
__global__ __launch_bounds__(TPB, 2) void walsh_mlp_kernel(
    const int* __restrict__ tt,
    const float* __restrict__ b1,
    const float* __restrict__ g1, const float* __restrict__ be1,
    const float* __restrict__ b2,
    const float* __restrict__ g2, const float* __restrict__ be2,
    const float* __restrict__ b3,
    const _Float16* __restrict__ wsW,
    float* __restrict__ out, int nrows)
{
    __shared__ __align__(16) _Float16 sAct[4][64][64]; // per-wave act tiles
    __shared__ float sP[7 * 64];   // g1,be1,g2,be2,b1,b2,b3
    __shared__ float entLUT[33];   // -p*log(p+1e-10), p=(2i)^2/4096

    const int tid = threadIdx.x;
    if (tid < 64) {
        sP[tid]       = g1[tid];
        sP[64 + tid]  = be1[tid];
        sP[128 + tid] = g2[tid];
        sP[192 + tid] = be2[tid];
        sP[256 + tid] = b1[tid];
        sP[320 + tid] = b2[tid];
        sP[384 + tid] = b3[tid];
    }
    if (tid < 33) {
        const float a = 2.0f * (float)tid;
        const float p = (a * a) * 2.44140625e-4f;   // /4096 exact
        entLUT[tid] = -(p * __logf(p + 1e-10f));
    }
    __syncthreads();

    const int row = blockIdx.x * TPB + tid;
    const int rowc = (row < nrows) ? row : (nrows - 1);  // clamp; no early exit

    // ---- load truth table row, convert to polar +-1 ----
    float v[64];
    const int4* t4 = reinterpret_cast<const int4*>(tt + (size_t)rowc * 64);
#pragma unroll
    for (int q = 0; q < 16; ++q) {
        int4 a = t4[q];
        v[4 * q + 0] = 1.0f - 2.0f * (float)a.x;
        v[4 * q + 1] = 1.0f - 2.0f * (float)a.y;
        v[4 * q + 2] = 1.0f - 2.0f * (float)a.z;
        v[4 * q + 3] = 1.0f - 2.0f * (float)a.w;
    }

    // ---- in-register FWHT (Sylvester order; == f @ H) ----
#pragma unroll
    for (int h = 1; h < 64; h <<= 1) {
#pragma unroll
        for (int i = 0; i < 64; ++i) {
            if ((i & h) == 0) {
                float a = v[i], b = v[i | h];
                v[i] = a + b;
                v[i | h] = a - b;
            }
        }
    }

    const float inv_n = 1.0f / 64.0f;
    float f[17];
    f[0] = v[0] * inv_n;  f[1] = v[1] * inv_n;  f[2] = v[2] * inv_n;
    f[3] = v[4] * inv_n;  f[4] = v[8] * inv_n;  f[5] = v[16] * inv_n;
    f[6] = v[32] * inv_n; f[7] = v[63] * inv_n;

    // ---- abs in place + single fused stats pass (walsh vals are exact even
    // ints in [-64,64]; Parseval: sumsq == 4096 exactly -> l2 const) ----
    float sumabs = 0.f, maxab = 0.f, cnt_sp = 0.f, cnt_lg = 0.f;
    float sum_hw = 0.f, bent = 0.f, ent = 0.f;
#pragma unroll
    for (int i = 0; i < 64; ++i) {
        float a = fabsf(v[i]);
        v[i] = a;
        sumabs += a;
        maxab = fmaxf(maxab, a);
        cnt_sp += (a < 6.4f) ? 1.0f : 0.0f;
        sum_hw += (a < 6.4f) ? 0.0f : (float)__popc(i);
        cnt_lg += (a > 32.0f) ? 1.0f : 0.0f;
        bent += fabsf(a - 8.0f);
        ent += entLUT[((int)a) >> 1];
    }

    f[8]  = cnt_sp * inv_n;
    f[9]  = maxab * inv_n;
    f[10] = sumabs * (1.0f / 4096.0f);
    f[11] = 0.015625f;  // l2 == 1/64 always (Parseval)
    f[12] = ent * 0.24044917348149316f;
    f[13] = (cnt_lg >= 0.5f && cnt_lg <= 2.5f) ? 1.0f : 0.0f;
    f[14] = fmaxf(0.0f, 0.5f - maxab * (1.0f / 128.0f)) * 2.0f;
    f[15] = sum_hw / (64.0f - cnt_sp + 1e-10f) * (1.0f / 6.0f);
    f[16] = (bent < 51.2f) ? 1.0f : 0.0f;

    // ---- top-16 in PACKED f16 (values are even ints <=64: f16-exact,
    // pk max/min exact). Pack (i, i+32): lo carries blocks 0,1; hi carries
    // blocks 2,3. Two packed Batcher-16 sorts handle 4 blocks in half the
    // ops; one packed bitonic top-merge does (0|1) and (2|3) simultaneously;
    // final cross-half merge via alignbit half-swap. ----
    h2 t2[16];
    {
        h2 hv[32];
#pragma unroll
        for (int i = 0; i < 32; ++i)
            hv[i] = __builtin_bit_cast(h2, pk_f16(v[i], v[i + 32]));

#pragma unroll
        for (int base = 0; base < 32; base += 16) {
#pragma unroll
            for (int p = 1; p < 16; p <<= 1) {
#pragma unroll
                for (int k = p; k >= 1; k >>= 1) {
#pragma unroll
                    for (int j = k & (p - 1); j + k < 16; j += 2 * k) {
#pragma unroll
                        for (int i = 0; i < k; ++i) {
                            if (i + j + k < 16 &&
                                (i + j) / (2 * p) == (i + j + k) / (2 * p))
                                ce2(hv[base + i + j], hv[base + i + j + k]);
                        }
                    }
                }
            }
        }
        // bitonic top-merge of two descending 16-lists (both halves at once)
        h2 mm[16];
#pragma unroll
        for (int i = 0; i < 16; ++i)
            mm[i] = __builtin_elementwise_max(hv[i], hv[31 - i]);
#pragma unroll
        for (int d = 8; d >= 1; d >>= 1) {
#pragma unroll
            for (int i = 0; i < 16; ++i)
                if ((i & d) == 0) ce2(mm[i], mm[i + d]);
        }
        // cross-half merge: lo list vs hi list (hi accessed via half-swap)
#pragma unroll
        for (int i = 0; i < 16; ++i) {
            unsigned m = __builtin_bit_cast(unsigned, mm[15 - i]);
            unsigned sw = __builtin_amdgcn_alignbit(m, m, 16);  // halves swapped
            t2[i] = __builtin_elementwise_max(mm[i], __builtin_bit_cast(h2, sw));
        }
#pragma unroll
        for (int d = 8; d >= 1; d >>= 1) {
#pragma unroll
            for (int i = 0; i < 16; ++i)
                if ((i & d) == 0) ce2(t2[i], t2[i + d]);
        }
        // scale by 1/64 (exponent shift: exact in f16)
        const h2 hs = {(_Float16)0.015625f, (_Float16)0.015625f};
#pragma unroll
        for (int i = 0; i < 16; ++i) t2[i] = t2[i] * hs;
    }

    // ================= MLP via MFMA =================
    const int w = tid >> 6, l = tid & 63;
    _Float16* actB = &sAct[w][0][0];

    // assemble act row l: halves 0..16 = f[0..16], 17..32 = top16, rest 0
    {
        unsigned wd[32];
#pragma unroll
        for (int j = 0; j < 8; ++j) wd[j] = pk_f16(f[2 * j], f[2 * j + 1]);
        {
            unsigned lo = (unsigned)__builtin_bit_cast(unsigned short,
                                                       (_Float16)f[16]);
            wd[8] = lo | (__builtin_bit_cast(unsigned, t2[0]) << 16);
        }
#pragma unroll
        for (int m = 0; m < 7; ++m)
            wd[9 + m] = (__builtin_bit_cast(unsigned, t2[2 * m + 1]) & 0xFFFFu)
                      | (__builtin_bit_cast(unsigned, t2[2 * m + 2]) << 16);
        wd[16] = __builtin_bit_cast(unsigned, t2[15]) & 0xFFFFu;
#pragma unroll
        for (int j = 17; j < 32; ++j) wd[j] = 0u;
#pragma unroll
        for (int c = 0; c < 8; ++c) {
            uint4 st;
            st.x = wd[4 * c + 0]; st.y = wd[4 * c + 1];
            st.z = wd[4 * c + 2]; st.w = wd[4 * c + 3];
            *reinterpret_cast<uint4*>(&actB[swz(l, c * 8)]) = st;
        }
    }
    asm volatile("s_waitcnt lgkmcnt(0)" ::: "memory");

    const int rowbase = blockIdx.x * TPB + w * 64;
    mfma_layer<false>(actB, wsW,         sP + 256, sP + 0,   sP + 64,
                      nullptr, 0, 0);
    mfma_layer<false>(actB, wsW + 8192,  sP + 320, sP + 128, sP + 192,
                      nullptr, 0, 0);
    mfma_layer<true >(actB, wsW + 16384, sP + 384, nullptr,  nullptr,
                      out, rowbase, nrows);
}

extern "C" void kernel_launch(void* const* d_in, const int* in_sizes, int n_in,
                              void* d_out, int out_size, void* d_ws, size_t ws_size,
                              hipStream_t stream) {
    const int*   tt  = (const int*)d_in[0];
    // d_in[1] is the Hadamard matrix H -- unused (in-register FWHT)
    const float* W1  = (const float*)d_in[2];
    const float* b1  = (const float*)d_in[3];
    const float* g1  = (const float*)d_in[4];
    const float* be1 = (const float*)d_in[5];
    const float* W2  = (const float*)d_in[6];
    const float* b2  = (const float*)d_in[7];
    const float* g2  = (const float*)d_in[8];
    const float* be2 = (const float*)d_in[9];
    const float* W3  = (const float*)d_in[10];
    const float* b3  = (const float*)d_in[11];
    float* out = (float*)d_out;
    _Float16* wsW = (_Float16*)d_ws;   // 48KB fragment-ordered hi/lo weights

    const int nrows = in_sizes[0] / 64;

    // stage weights into fragment order (tiny; runs in-stream each call)
    hipLaunchKernelGGL(weight_stage_kernel, dim3(48), dim3(256), 0, stream,
                       W1, W2, W3, wsW);

    const int grid = (nrows + TPB - 1) / TPB;
    hipLaunchKernelGGL(walsh_mlp_kernel, dim3(grid), dim3(TPB), 0, stream,
                       tt, b1, g1, be1, b2, g2, be2, b3, wsW, out, nrows);
}